// Round 4
// baseline (2002.563 us; speedup 1.0000x reference)
//
#include <hip/hip_runtime.h>
#include <hip/hip_bf16.h>
#include <math.h>

#define B_ 2
#define S_ 2048
#define E_ 768
#define H_ 12
#define D_ 64
#define M_ (B_*S_)   // 4096 rows total

// ---------------------------------------------------------------------------
// Kernel 1: QKV projection (+bias) with RoPE applied to Q and K.
// grid (M/64, E/64, 3) block 256. Each n-tile (64 cols) is exactly one head.
// Out layout: [B, H, S, D] fp32.  All tensors fp32 (reference dtypes).
// ---------------------------------------------------------------------------
__global__ __launch_bounds__(256) void qkv_proj_kernel(
    const float* __restrict__ q_in, const float* __restrict__ k_in, const float* __restrict__ v_in,
    const float* __restrict__ wq, const float* __restrict__ bq,
    const float* __restrict__ wk, const float* __restrict__ bk,
    const float* __restrict__ wv, const float* __restrict__ bv,
    float* __restrict__ Qr, float* __restrict__ Kr, float* __restrict__ Vv)
{
    const int z = blockIdx.z;
    const float* __restrict__ X    = (z == 0) ? q_in : (z == 1) ? k_in : v_in;
    const float* __restrict__ W    = (z == 0) ? wq   : (z == 1) ? wk   : wv;
    const float* __restrict__ bias = (z == 0) ? bq   : (z == 1) ? bk   : bv;
    float* __restrict__ Out        = (z == 0) ? Qr   : (z == 1) ? Kr   : Vv;

    __shared__ float As[64][65];   // +1 pad: kills power-of-2 bank stride
    __shared__ float Ws[64][65];

    const int m0 = blockIdx.x * 64;
    const int h  = blockIdx.y;            // head index == n-tile index
    const int n0 = h * 64;
    const int t  = threadIdx.x;
    const int tn = t & 15;                // column-pair group 0..15
    const int tm = t >> 4;                // row group 0..15

    float acc[4][4];
    #pragma unroll
    for (int i = 0; i < 4; ++i)
        #pragma unroll
        for (int j = 0; j < 4; ++j) acc[i][j] = 0.f;

    for (int k0 = 0; k0 < E_; k0 += 64) {
        __syncthreads();
        #pragma unroll
        for (int i = 0; i < 16; ++i) {
            int idx = t + i * 256;        // 0..4095
            int r = idx >> 6, c = idx & 63;
            As[r][c] = X[(size_t)(m0 + r) * E_ + k0 + c];
            Ws[r][c] = W[(size_t)(n0 + r) * E_ + k0 + c];
        }
        __syncthreads();
        #pragma unroll
        for (int kk = 0; kk < 64; ++kk) {
            float a0 = As[tm][kk], a1 = As[tm + 16][kk],
                  a2 = As[tm + 32][kk], a3 = As[tm + 48][kk];
            float w0 = Ws[2 * tn][kk],      w1 = Ws[2 * tn + 1][kk],
                  w2 = Ws[2 * tn + 32][kk], w3 = Ws[2 * tn + 33][kk];
            acc[0][0] += a0 * w0; acc[0][1] += a0 * w1; acc[0][2] += a0 * w2; acc[0][3] += a0 * w3;
            acc[1][0] += a1 * w0; acc[1][1] += a1 * w1; acc[1][2] += a1 * w2; acc[1][3] += a1 * w3;
            acc[2][0] += a2 * w0; acc[2][1] += a2 * w1; acc[2][2] += a2 * w2; acc[2][3] += a2 * w3;
            acc[3][0] += a3 * w0; acc[3][1] += a3 * w1; acc[3][2] += a3 * w2; acc[3][3] += a3 * w3;
        }
    }

    // Epilogue: bias, RoPE (z<2), store to [B,H,S,D]
    const float ln1e4 = 9.210340371976184f;  // ln(10000)
    #pragma unroll
    for (int jc = 0; jc < 2; ++jc) {
        const int c = 2 * tn + 32 * jc;      // even column within head (= d)
        const float bv0 = bias[n0 + c];
        const float bv1 = bias[n0 + c + 1];
        // inv_freq = 10000^(-c/64): pair index i = c/2, exponent 2i/dim = c/64
        const float inv_freq = expf(-((float)c / 64.f) * ln1e4);
        #pragma unroll
        for (int i = 0; i < 4; ++i) {
            const int r = tm + 16 * i;
            const int m = m0 + r;
            const int bb = m >> 11;          // /2048
            const int s  = m & (S_ - 1);
            float v0 = acc[i][2 * jc]     + bv0;
            float v1 = acc[i][2 * jc + 1] + bv1;
            if (z < 2) {
                float sn, cs;
                sincosf((float)s * inv_freq, &sn, &cs);
                float r0 = v0 * cs - v1 * sn;   // x*cos + rotate_half(x)*sin
                float r1 = v1 * cs + v0 * sn;
                v0 = r0; v1 = r1;
            }
            size_t o = (((size_t)bb * H_ + h) * S_ + s) * (size_t)D_ + c;
            Out[o]     = v0;
            Out[o + 1] = v1;
        }
    }
}

// ---------------------------------------------------------------------------
// Kernel 2: flash-style attention with online softmax.
// grid (S/32, H, B) block 256. Each block: 32 q-rows x full K sweep (64-key tiles).
// Thread mapping (both phases): q = t>>3 (0..31), sub-lane dr = t&7.
// Mask encoding auto-detected (falsified bool-bytes in R3: detector chose
// int32 and output was bit-identical — keeping detector as cheap insurance).
// ---------------------------------------------------------------------------
__global__ __launch_bounds__(256) void attn_kernel(
    const float* __restrict__ Qr, const float* __restrict__ Kr, const float* __restrict__ Vv,
    const float* __restrict__ pb, const void* __restrict__ mask_raw, const float* __restrict__ coeff,
    float* __restrict__ Att)
{
    const int q0 = blockIdx.x * 32;
    const int h  = blockIdx.y;
    const int b  = blockIdx.z;
    const int t  = threadIdx.x;
    const int q  = t >> 3;
    const int dr = t & 7;

    __shared__ float Qs[32][65];
    __shared__ float Ks[64][65];
    __shared__ float Vs[64][65];
    __shared__ float Ss[32][65];      // softmax numerators p
    __shared__ float pbk[64];
    __shared__ int   mk[64];
    __shared__ int   modeSh[2];       // [0]: any byte@off%4!=0  [1]: any byte@off%8==4

    // ---- mask-encoding detection ----
    if (t == 0) { modeSh[0] = 0; modeSh[1] = 0; }
    __syncthreads();
    {
        const unsigned char* mb = (const unsigned char*)mask_raw;
        int lb = 0;
        if (t < 256) { int off = t; if (off & 3) lb = mb[off]; }
        int li = 0;
        if (t < 256) li = mb[4 + 8 * t];
        if (lb) atomicOr(&modeSh[0], 1);
        if (li) atomicOr(&modeSh[1], 1);
    }
    __syncthreads();
    const int mmode = modeSh[0] ? 0 : (modeSh[1] ? 1 : 2);  // 0=byte,1=int32,2=int64

    const float ch = coeff[h];
    const size_t base = ((size_t)b * H_ + h) * S_ * (size_t)D_;
    const float* __restrict__ Qp = Qr + base;
    const float* __restrict__ Kp = Kr + base;
    const float* __restrict__ Vp = Vv + base;

    // Q tile: 32x64
    #pragma unroll
    for (int i = 0; i < 8; ++i) {
        int idx = t + i * 256;        // 0..2047
        int r = idx >> 6, c = idx & 63;
        Qs[r][c] = Qp[(size_t)(q0 + r) * D_ + c];
    }

    const float pbq = pb[b * S_ + q0 + q];

    float O[8];
    #pragma unroll
    for (int j = 0; j < 8; ++j) O[j] = 0.f;
    float mreg = -1e30f, lreg = 0.f;

    const int kb = dr * 8;            // this thread's key offset in tile
    const int d0 = dr * 8;            // this thread's dim offset in tile

    for (int kt = 0; kt < S_ / 64; ++kt) {
        const int k0 = kt * 64;
        __syncthreads();              // prev PV done before overwriting Ks/Vs
        #pragma unroll
        for (int i = 0; i < 16; ++i) {
            int idx = t + i * 256;    // 0..4095
            int r = idx >> 6, c = idx & 63;
            Ks[r][c] = Kp[(size_t)(k0 + r) * D_ + c];
            Vs[r][c] = Vp[(size_t)(k0 + r) * D_ + c];
        }
        if (t < 64) {
            int gi = b * S_ + k0 + t;
            pbk[t] = pb[gi];
            int mv;
            if (mmode == 0)      mv = ((const unsigned char*)mask_raw)[gi];
            else if (mmode == 1) mv = ((const int*)mask_raw)[gi];
            else                 mv = (int)(((const long long*)mask_raw)[gi] != 0);
            mk[t] = mv;
        }
        __syncthreads();

        // ---- scores: row q, keys kb..kb+7 ----
        float sc[8];
        int   mloc[8];
        #pragma unroll
        for (int j = 0; j < 8; ++j) sc[j] = 0.f;
        #pragma unroll
        for (int kk = 0; kk < 64; ++kk) {
            float qv = Qs[q][kk];
            #pragma unroll
            for (int j = 0; j < 8; ++j) sc[j] += qv * Ks[kb + j][kk];
        }
        float mx = -1e30f;
        #pragma unroll
        for (int j = 0; j < 8; ++j) {
            mloc[j] = mk[kb + j];
            float s = sc[j] * 0.125f + ch * (pbq - pbk[kb + j]);
            s = mloc[j] ? s : -1e30f;
            sc[j] = s;
            mx = fmaxf(mx, s);
        }
        // row max across the 8 lanes sharing q
        mx = fmaxf(mx, __shfl_xor(mx, 1));
        mx = fmaxf(mx, __shfl_xor(mx, 2));
        mx = fmaxf(mx, __shfl_xor(mx, 4));

        const float m_new = fmaxf(mreg, mx);
        const float alpha = __expf(mreg - m_new);
        float psum = 0.f;
        #pragma unroll
        for (int j = 0; j < 8; ++j) {
            float p = mloc[j] ? __expf(sc[j] - m_new) : 0.f;  // masked never contributes
            Ss[q][kb + j] = p;
            psum += p;
        }
        psum += __shfl_xor(psum, 1);
        psum += __shfl_xor(psum, 2);
        psum += __shfl_xor(psum, 4);
        lreg = lreg * alpha + psum;
        mreg = m_new;
        __syncthreads();              // Ss visible to all lanes of row q

        // ---- PV: row q, dims d0..d0+7 ----
        #pragma unroll
        for (int j = 0; j < 8; ++j) O[j] *= alpha;
        #pragma unroll
        for (int k = 0; k < 64; ++k) {
            float p = Ss[q][k];
            #pragma unroll
            for (int j = 0; j < 8; ++j) O[j] += p * Vs[k][d0 + j];
        }
    }

    // epilogue: normalize, store merged-head layout [B,S,E] fp32
    const float rl = 1.f / lreg;
    const size_t ob = ((size_t)b * S_ + (q0 + q)) * (size_t)E_ + h * D_ + d0;
    #pragma unroll
    for (int j = 0; j < 8; ++j) Att[ob + j] = O[j] * rl;
}

// ---------------------------------------------------------------------------
// Kernel 3: output projection  out = Att @ fc_w^T + fc_b  -> fp32 (ref dtype)
// grid (M/64, E/64) block 256
// ---------------------------------------------------------------------------
__global__ __launch_bounds__(256) void fc_kernel(
    const float* __restrict__ Xin, const float* __restrict__ W,
    const float* __restrict__ bias, float* __restrict__ Out)
{
    __shared__ float As[64][65];
    __shared__ float Ws[64][65];

    const int m0 = blockIdx.x * 64;
    const int n0 = blockIdx.y * 64;
    const int t  = threadIdx.x;
    const int tn = t & 15;
    const int tm = t >> 4;

    float acc[4][4];
    #pragma unroll
    for (int i = 0; i < 4; ++i)
        #pragma unroll
        for (int j = 0; j < 4; ++j) acc[i][j] = 0.f;

    for (int k0 = 0; k0 < E_; k0 += 64) {
        __syncthreads();
        #pragma unroll
        for (int i = 0; i < 16; ++i) {
            int idx = t + i * 256;
            int r = idx >> 6, c = idx & 63;
            As[r][c] = Xin[(size_t)(m0 + r) * E_ + k0 + c];
            Ws[r][c] = W[(size_t)(n0 + r) * E_ + k0 + c];
        }
        __syncthreads();
        #pragma unroll
        for (int kk = 0; kk < 64; ++kk) {
            float a0 = As[tm][kk], a1 = As[tm + 16][kk],
                  a2 = As[tm + 32][kk], a3 = As[tm + 48][kk];
            float w0 = Ws[2 * tn][kk],      w1 = Ws[2 * tn + 1][kk],
                  w2 = Ws[2 * tn + 32][kk], w3 = Ws[2 * tn + 33][kk];
            acc[0][0] += a0 * w0; acc[0][1] += a0 * w1; acc[0][2] += a0 * w2; acc[0][3] += a0 * w3;
            acc[1][0] += a1 * w0; acc[1][1] += a1 * w1; acc[1][2] += a1 * w2; acc[1][3] += a1 * w3;
            acc[2][0] += a2 * w0; acc[2][1] += a2 * w1; acc[2][2] += a2 * w2; acc[2][3] += a2 * w3;
            acc[3][0] += a3 * w0; acc[3][1] += a3 * w1; acc[3][2] += a3 * w2; acc[3][3] += a3 * w3;
        }
    }

    #pragma unroll
    for (int jc = 0; jc < 2; ++jc) {
        const int c = 2 * tn + 32 * jc;
        const float bv0 = bias[n0 + c];
        const float bv1 = bias[n0 + c + 1];
        #pragma unroll
        for (int i = 0; i < 4; ++i) {
            const int r = tm + 16 * i;
            const int m = m0 + r;
            size_t o = (size_t)m * E_ + n0 + c;
            Out[o]     = acc[i][2 * jc]     + bv0;
            Out[o + 1] = acc[i][2 * jc + 1] + bv1;
        }
    }
}

// ---------------------------------------------------------------------------
extern "C" void kernel_launch(void* const* d_in, const int* in_sizes, int n_in,
                              void* d_out, int out_size, void* d_ws, size_t ws_size,
                              hipStream_t stream)
{
    const float* q_in  = (const float*)d_in[0];
    const float* k_in  = (const float*)d_in[1];
    const float* v_in  = (const float*)d_in[2];
    const float* pb    = (const float*)d_in[3];
    const void*  mask  = (const void*)d_in[4];   // encoding auto-detected in-kernel
    const float* wq    = (const float*)d_in[5];
    const float* bq    = (const float*)d_in[6];
    const float* wk    = (const float*)d_in[7];
    const float* bk    = (const float*)d_in[8];
    const float* wv    = (const float*)d_in[9];
    const float* bv    = (const float*)d_in[10];
    const float* fw    = (const float*)d_in[11];
    const float* fb    = (const float*)d_in[12];
    const float* coeff = (const float*)d_in[13];
    float* out = (float*)d_out;                  // reference output dtype: fp32

    const size_t per = (size_t)B_ * H_ * S_ * D_;   // 3,145,728 floats
    float* Qr  = (float*)d_ws;
    float* Kr  = Qr + per;
    float* Vv  = Kr + per;
    float* Att = Vv + per;                           // [B,S,E] fp32

    qkv_proj_kernel<<<dim3(M_ / 64, E_ / 64, 3), 256, 0, stream>>>(
        q_in, k_in, v_in, wq, bq, wk, bk, wv, bv, Qr, Kr, Vv);

    attn_kernel<<<dim3(S_ / 32, H_, B_), 256, 0, stream>>>(
        Qr, Kr, Vv, pb, mask, coeff, Att);

    fc_kernel<<<dim3(M_ / 64, E_ / 64), 256, 0, stream>>>(Att, fw, fb, out);
}

// Round 5
// 606.752 us; speedup vs baseline: 3.3005x; 3.3005x over previous
//
#include <hip/hip_runtime.h>
#include <hip/hip_bf16.h>
#include <math.h>

#define B_ 2
#define S_ 2048
#define E_ 768
#define H_ 12
#define D_ 64
#define M_ (B_*S_)   // 4096 rows total

typedef unsigned short ush;
using short8 = __attribute__((ext_vector_type(8))) short;   // 8 bf16 (4 VGPRs)
using f32x4  = __attribute__((ext_vector_type(4))) float;   // MFMA C/D

__device__ __forceinline__ ush f2b(float x) {               // fp32 -> bf16 RNE
    union { float f; unsigned u; } v; v.f = x;
    unsigned r = v.u + 0x7fffu + ((v.u >> 16) & 1u);
    return (ush)(r >> 16);
}

// ---------------------------------------------------------------------------
// Kernel 1: QKV projection (+bias), RoPE on Q/K. fp32 GEMM (unchanged core),
// epilogue now emits bf16: Q,K as [B,H,S,D]; V transposed as [B,H,D,S] so the
// attention kernel's MFMA B-fragment reads are contiguous.
// grid (M/64, E/64=H, 3) block 256.
// ---------------------------------------------------------------------------
__global__ __launch_bounds__(256) void qkv_proj_kernel(
    const float* __restrict__ q_in, const float* __restrict__ k_in, const float* __restrict__ v_in,
    const float* __restrict__ wq, const float* __restrict__ bq,
    const float* __restrict__ wk, const float* __restrict__ bk,
    const float* __restrict__ wv, const float* __restrict__ bv,
    ush* __restrict__ Qb, ush* __restrict__ Kb, ush* __restrict__ Vtb)
{
    const int z = blockIdx.z;
    const float* __restrict__ X    = (z == 0) ? q_in : (z == 1) ? k_in : v_in;
    const float* __restrict__ W    = (z == 0) ? wq   : (z == 1) ? wk   : wv;
    const float* __restrict__ bias = (z == 0) ? bq   : (z == 1) ? bk   : bv;

    __shared__ float As[64][65];
    __shared__ float Ws[64][65];

    const int m0 = blockIdx.x * 64;
    const int h  = blockIdx.y;
    const int n0 = h * 64;
    const int t  = threadIdx.x;
    const int tn = t & 15;
    const int tm = t >> 4;

    float acc[4][4];
    #pragma unroll
    for (int i = 0; i < 4; ++i)
        #pragma unroll
        for (int j = 0; j < 4; ++j) acc[i][j] = 0.f;

    for (int k0 = 0; k0 < E_; k0 += 64) {
        __syncthreads();
        #pragma unroll
        for (int i = 0; i < 16; ++i) {
            int idx = t + i * 256;
            int r = idx >> 6, c = idx & 63;
            As[r][c] = X[(size_t)(m0 + r) * E_ + k0 + c];
            Ws[r][c] = W[(size_t)(n0 + r) * E_ + k0 + c];
        }
        __syncthreads();
        #pragma unroll
        for (int kk = 0; kk < 64; ++kk) {
            float a0 = As[tm][kk], a1 = As[tm + 16][kk],
                  a2 = As[tm + 32][kk], a3 = As[tm + 48][kk];
            float w0 = Ws[2 * tn][kk],      w1 = Ws[2 * tn + 1][kk],
                  w2 = Ws[2 * tn + 32][kk], w3 = Ws[2 * tn + 33][kk];
            acc[0][0] += a0 * w0; acc[0][1] += a0 * w1; acc[0][2] += a0 * w2; acc[0][3] += a0 * w3;
            acc[1][0] += a1 * w0; acc[1][1] += a1 * w1; acc[1][2] += a1 * w2; acc[1][3] += a1 * w3;
            acc[2][0] += a2 * w0; acc[2][1] += a2 * w1; acc[2][2] += a2 * w2; acc[2][3] += a2 * w3;
            acc[3][0] += a3 * w0; acc[3][1] += a3 * w1; acc[3][2] += a3 * w2; acc[3][3] += a3 * w3;
        }
    }

    const float ln1e4 = 9.210340371976184f;  // ln(10000)
    #pragma unroll
    for (int jc = 0; jc < 2; ++jc) {
        const int c = 2 * tn + 32 * jc;      // even d within head
        const float bv0 = bias[n0 + c];
        const float bv1 = bias[n0 + c + 1];
        const float inv_freq = expf(-((float)c / 64.f) * ln1e4);
        #pragma unroll
        for (int i = 0; i < 4; ++i) {
            const int r = tm + 16 * i;
            const int m = m0 + r;
            const int bb = m >> 11;
            const int s  = m & (S_ - 1);
            float v0 = acc[i][2 * jc]     + bv0;
            float v1 = acc[i][2 * jc + 1] + bv1;
            if (z < 2) {
                float sn, cs;
                sincosf((float)s * inv_freq, &sn, &cs);
                float r0 = v0 * cs - v1 * sn;
                float r1 = v1 * cs + v0 * sn;
                ush* Ob = (z == 0) ? Qb : Kb;
                size_t o = (((size_t)bb * H_ + h) * S_ + s) * (size_t)D_ + c;
                unsigned packed = (unsigned)f2b(r0) | ((unsigned)f2b(r1) << 16);
                *(unsigned*)&Ob[o] = packed;
            } else {
                size_t ot = (((size_t)bb * H_ + h) * D_ + c) * (size_t)S_ + s;
                Vtb[ot]      = f2b(v0);
                Vtb[ot + S_] = f2b(v1);
            }
        }
    }
}

// ---------------------------------------------------------------------------
// Kernel 2: MFMA flash attention. grid (S/64, H, B), block 256 (4 waves).
// Each wave owns a 16-row Q strip; block shares 64-key K/V tiles in LDS.
// mfma_f32_16x16x32_bf16. C/D: col=lane&15,row=quad*4+reg (m89).
// A-frag: A[m=lane&15][k=quad*8+j] (m120). LDS rows padded to 72 shorts
// (144B): frag reads are 2-way bank-aliased = free.
// ---------------------------------------------------------------------------
__global__ __launch_bounds__(256) void attn_kernel(
    const ush* __restrict__ Qb, const ush* __restrict__ Kb, const ush* __restrict__ Vtb,
    const float* __restrict__ pb, const int* __restrict__ mask, const float* __restrict__ coeff,
    float* __restrict__ Att)
{
    __shared__ ush  Ks[64 * 72];       // [key][d]  pitch 72
    __shared__ ush  Vt[64 * 72];       // [d][key]  pitch 72
    __shared__ ush  Ps[4 * 16 * 72];   // per-wave P rows [q][key]
    __shared__ float pbk_s[64];
    __shared__ float mb_s[64];

    const int q0 = blockIdx.x * 64;
    const int h  = blockIdx.y;
    const int b  = blockIdx.z;
    const int t  = threadIdx.x;
    const int wv = t >> 6;             // wave 0..3
    const int lane = t & 63;
    const int quad = lane >> 4;        // 0..3
    const int l16  = lane & 15;

    const int bh = b * H_ + h;
    const float ch = coeff[h];

    // Q A-frags (2 k-steps over D=64), loaded straight from global
    const int qrow = q0 + wv * 16 + l16;
    short8 aQ[2];
    #pragma unroll
    for (int ks = 0; ks < 2; ++ks)
        aQ[ks] = *(const short8*)&Qb[((size_t)bh * S_ + qrow) * D_ + quad * 8 + ks * 32];

    // per-row (reg) coeff*pb[q] ; rows handled by this lane: quad*4+r
    float hp[4];
    #pragma unroll
    for (int r = 0; r < 4; ++r)
        hp[r] = ch * pb[b * S_ + q0 + wv * 16 + quad * 4 + r];

    f32x4 O[4];                        // [d-group], rows=q
    #pragma unroll
    for (int g = 0; g < 4; ++g) O[g] = (f32x4){0.f, 0.f, 0.f, 0.f};
    float mrow[4] = {-1e30f, -1e30f, -1e30f, -1e30f};
    float lrow[4] = {0.f, 0.f, 0.f, 0.f};

    for (int kt = 0; kt < S_ / 64; ++kt) {
        const int k0 = kt * 64;
        __syncthreads();               // prior tile's frag reads done

        // stage K tile (contiguous 8KB) and Vt tile (64 rows x 128B, stride S)
        {
            const uint4* srcK = (const uint4*)(Kb + ((size_t)bh * S_ + k0) * D_);
            #pragma unroll
            for (int it = 0; it < 2; ++it) {
                int idx = t + it * 256;              // 0..511
                int row = idx >> 3, chk = idx & 7;
                *(uint4*)&Ks[row * 72 + chk * 8] = srcK[idx];
                const uint4* srcV = (const uint4*)(Vtb + ((size_t)bh * D_ + row) * S_ + k0);
                *(uint4*)&Vt[row * 72 + chk * 8] = srcV[chk];
            }
        }
        if (t < 64) {
            int gi = b * S_ + k0 + t;
            pbk_s[t] = pb[gi];
            mb_s[t]  = mask[gi] ? 0.f : -1e30f;
        }
        __syncthreads();

        // ---- QK^T: Sc[cg] = 16x16 scores, keys cg*16.. ----
        f32x4 Sc[4];
        #pragma unroll
        for (int cg = 0; cg < 4; ++cg) Sc[cg] = (f32x4){0.f, 0.f, 0.f, 0.f};
        #pragma unroll
        for (int ks = 0; ks < 2; ++ks) {
            #pragma unroll
            for (int cg = 0; cg < 4; ++cg) {
                short8 bK = *(const short8*)&Ks[(cg * 16 + l16) * 72 + quad * 8 + ks * 32];
                Sc[cg] = __builtin_amdgcn_mfma_f32_16x16x32_bf16(aQ[ks], bK, Sc[cg], 0, 0, 0);
            }
        }

        // ---- bias + mask + online softmax ----
        float cpb[4], mbv[4];
        #pragma unroll
        for (int cg = 0; cg < 4; ++cg) {
            cpb[cg] = ch * pbk_s[cg * 16 + l16];
            mbv[cg] = mb_s[cg * 16 + l16];
        }
        float mx[4];
        #pragma unroll
        for (int r = 0; r < 4; ++r) mx[r] = -1e30f;
        float sv[4][4];
        #pragma unroll
        for (int cg = 0; cg < 4; ++cg)
            #pragma unroll
            for (int r = 0; r < 4; ++r) {
                float s = Sc[cg][r] * 0.125f + hp[r] - cpb[cg] + mbv[cg];
                sv[cg][r] = s;
                mx[r] = fmaxf(mx[r], s);
            }
        #pragma unroll
        for (int r = 0; r < 4; ++r) {                  // reduce over 16 lanes of quad
            mx[r] = fmaxf(mx[r], __shfl_xor(mx[r], 1));
            mx[r] = fmaxf(mx[r], __shfl_xor(mx[r], 2));
            mx[r] = fmaxf(mx[r], __shfl_xor(mx[r], 4));
            mx[r] = fmaxf(mx[r], __shfl_xor(mx[r], 8));
        }
        float alpha[4], psum[4];
        #pragma unroll
        for (int r = 0; r < 4; ++r) {
            float mn = fmaxf(mrow[r], mx[r]);
            alpha[r] = __expf(mrow[r] - mn);
            mrow[r] = mn;
            psum[r] = 0.f;
        }
        #pragma unroll
        for (int cg = 0; cg < 4; ++cg)
            #pragma unroll
            for (int r = 0; r < 4; ++r) {
                float s = sv[cg][r];
                float p = (s > -1e29f) ? __expf(s - mrow[r]) : 0.f;
                sv[cg][r] = p;
                psum[r] += p;
            }
        #pragma unroll
        for (int r = 0; r < 4; ++r) {
            psum[r] += __shfl_xor(psum[r], 1);
            psum[r] += __shfl_xor(psum[r], 2);
            psum[r] += __shfl_xor(psum[r], 4);
            psum[r] += __shfl_xor(psum[r], 8);
            lrow[r] = lrow[r] * alpha[r] + psum[r];
        }

        // ---- write P (C-layout) to LDS, rescale O ----
        #pragma unroll
        for (int cg = 0; cg < 4; ++cg)
            #pragma unroll
            for (int r = 0; r < 4; ++r)
                Ps[(wv * 16 + quad * 4 + r) * 72 + cg * 16 + l16] = f2b(sv[cg][r]);
        #pragma unroll
        for (int g = 0; g < 4; ++g)
            #pragma unroll
            for (int r = 0; r < 4; ++r) O[g][r] *= alpha[r];

        // ---- PV: O[g] += P(16x64) * V(64x16 per group) ----
        #pragma unroll
        for (int ks = 0; ks < 2; ++ks) {
            short8 aP = *(const short8*)&Ps[(wv * 16 + l16) * 72 + quad * 8 + ks * 32];
            #pragma unroll
            for (int g = 0; g < 4; ++g) {
                short8 bV = *(const short8*)&Vt[(g * 16 + l16) * 72 + quad * 8 + ks * 32];
                O[g] = __builtin_amdgcn_mfma_f32_16x16x32_bf16(aP, bV, O[g], 0, 0, 0);
            }
        }
    }

    // epilogue: normalize, store [B,S,E] fp32
    #pragma unroll
    for (int r = 0; r < 4; ++r) {
        const float rl = 1.f / lrow[r];
        const size_t ob = ((size_t)b * S_ + q0 + wv * 16 + quad * 4 + r) * E_ + h * 64;
        #pragma unroll
        for (int g = 0; g < 4; ++g)
            Att[ob + g * 16 + l16] = O[g][r] * rl;
    }
}

// ---------------------------------------------------------------------------
// Kernel 3: output projection  out = Att @ fc_w^T + fc_b  -> fp32
// grid (M/64, E/64) block 256
// ---------------------------------------------------------------------------
__global__ __launch_bounds__(256) void fc_kernel(
    const float* __restrict__ Xin, const float* __restrict__ W,
    const float* __restrict__ bias, float* __restrict__ Out)
{
    __shared__ float As[64][65];
    __shared__ float Ws[64][65];

    const int m0 = blockIdx.x * 64;
    const int n0 = blockIdx.y * 64;
    const int t  = threadIdx.x;
    const int tn = t & 15;
    const int tm = t >> 4;

    float acc[4][4];
    #pragma unroll
    for (int i = 0; i < 4; ++i)
        #pragma unroll
        for (int j = 0; j < 4; ++j) acc[i][j] = 0.f;

    for (int k0 = 0; k0 < E_; k0 += 64) {
        __syncthreads();
        #pragma unroll
        for (int i = 0; i < 16; ++i) {
            int idx = t + i * 256;
            int r = idx >> 6, c = idx & 63;
            As[r][c] = Xin[(size_t)(m0 + r) * E_ + k0 + c];
            Ws[r][c] = W[(size_t)(n0 + r) * E_ + k0 + c];
        }
        __syncthreads();
        #pragma unroll
        for (int kk = 0; kk < 64; ++kk) {
            float a0 = As[tm][kk], a1 = As[tm + 16][kk],
                  a2 = As[tm + 32][kk], a3 = As[tm + 48][kk];
            float w0 = Ws[2 * tn][kk],      w1 = Ws[2 * tn + 1][kk],
                  w2 = Ws[2 * tn + 32][kk], w3 = Ws[2 * tn + 33][kk];
            acc[0][0] += a0 * w0; acc[0][1] += a0 * w1; acc[0][2] += a0 * w2; acc[0][3] += a0 * w3;
            acc[1][0] += a1 * w0; acc[1][1] += a1 * w1; acc[1][2] += a1 * w2; acc[1][3] += a1 * w3;
            acc[2][0] += a2 * w0; acc[2][1] += a2 * w1; acc[2][2] += a2 * w2; acc[2][3] += a2 * w3;
            acc[3][0] += a3 * w0; acc[3][1] += a3 * w1; acc[3][2] += a3 * w2; acc[3][3] += a3 * w3;
        }
    }

    #pragma unroll
    for (int jc = 0; jc < 2; ++jc) {
        const int c = 2 * tn + 32 * jc;
        const float bv0 = bias[n0 + c];
        const float bv1 = bias[n0 + c + 1];
        #pragma unroll
        for (int i = 0; i < 4; ++i) {
            const int r = tm + 16 * i;
            size_t o = (size_t)(m0 + r) * E_ + n0 + c;
            Out[o]     = acc[i][2 * jc]     + bv0;
            Out[o + 1] = acc[i][2 * jc + 1] + bv1;
        }
    }
}

// ---------------------------------------------------------------------------
extern "C" void kernel_launch(void* const* d_in, const int* in_sizes, int n_in,
                              void* d_out, int out_size, void* d_ws, size_t ws_size,
                              hipStream_t stream)
{
    const float* q_in  = (const float*)d_in[0];
    const float* k_in  = (const float*)d_in[1];
    const float* v_in  = (const float*)d_in[2];
    const float* pb    = (const float*)d_in[3];
    const int*   mask  = (const int*)d_in[4];
    const float* wq    = (const float*)d_in[5];
    const float* bq    = (const float*)d_in[6];
    const float* wk    = (const float*)d_in[7];
    const float* bk    = (const float*)d_in[8];
    const float* wv    = (const float*)d_in[9];
    const float* bv    = (const float*)d_in[10];
    const float* fw    = (const float*)d_in[11];
    const float* fb    = (const float*)d_in[12];
    const float* coeff = (const float*)d_in[13];
    float* out = (float*)d_out;

    const size_t per = (size_t)B_ * H_ * S_ * D_;   // 3,145,728 elements
    float* Att = (float*)d_ws;                       // [B,S,E] fp32
    ush*   Qb  = (ush*)(Att + per);                  // bf16 [B,H,S,D]
    ush*   Kb  = Qb + per;
    ush*   Vtb = Kb + per;                           // bf16 [B,H,D,S]

    qkv_proj_kernel<<<dim3(M_ / 64, E_ / 64, 3), 256, 0, stream>>>(
        q_in, k_in, v_in, wq, bq, wk, bk, wv, bv, Qb, Kb, Vtb);

    attn_kernel<<<dim3(S_ / 64, H_, B_), 256, 0, stream>>>(
        Qb, Kb, Vtb, pb, mask, coeff, Att);

    fc_kernel<<<dim3(M_ / 64, E_ / 64), 256, 0, stream>>>(Att, fw, fb, out);
}

// Round 6
// 515.312 us; speedup vs baseline: 3.8861x; 1.1774x over previous
//
#include <hip/hip_runtime.h>
#include <hip/hip_bf16.h>
#include <math.h>

#define B_ 2
#define S_ 2048
#define E_ 768
#define H_ 12
#define D_ 64
#define M_ (B_*S_)   // 4096 rows total

typedef unsigned short ush;
using short8 = __attribute__((ext_vector_type(8))) short;   // 8 bf16 (4 VGPRs)
using f32x4  = __attribute__((ext_vector_type(4))) float;   // MFMA C/D

__device__ __forceinline__ ush f2b(float x) {               // fp32 -> bf16 RNE
    union { float f; unsigned u; } v; v.f = x;
    unsigned r = v.u + 0x7fffu + ((v.u >> 16) & 1u);
    return (ush)(r >> 16);
}

// split fp32 pair -> packed bf16 hi (truncated) + lo (RNE of exact residual)
__device__ __forceinline__ void cvt_pair(float x, float y, unsigned &h, unsigned &l) {
    unsigned bx = __float_as_uint(x), by = __float_as_uint(y);
    unsigned hx = bx & 0xFFFF0000u, hy = by & 0xFFFF0000u;
    h = (bx >> 16) | hy;
    float rx = x - __uint_as_float(hx);   // exact
    float ry = y - __uint_as_float(hy);   // exact
    l = (unsigned)f2b(rx) | ((unsigned)f2b(ry) << 16);
}

// ---------------------------------------------------------------------------
// Kernel 1: QKV projection via split-bf16 MFMA (fp32-equivalent precision).
// C = X @ W^T + bias. Tile 128x128, BK=32, block 256 (4 waves, 2x2 of 64x64).
// Epilogue: RoPE (z<2) -> Qb/Kb bf16 [B,H,S,D]; V (z=2) -> Vtb bf16 [B,H,D,S].
// grid (M/128, E/128, 3).
// ---------------------------------------------------------------------------
__global__ __launch_bounds__(256) void qkv_mfma_kernel(
    const float* __restrict__ q_in, const float* __restrict__ k_in, const float* __restrict__ v_in,
    const float* __restrict__ wq, const float* __restrict__ bq,
    const float* __restrict__ wk, const float* __restrict__ bk,
    const float* __restrict__ wv, const float* __restrict__ bv,
    ush* __restrict__ Qb, ush* __restrict__ Kb, ush* __restrict__ Vtb)
{
    const int z = blockIdx.z;
    const float* __restrict__ X    = (z == 0) ? q_in : (z == 1) ? k_in : v_in;
    const float* __restrict__ W    = (z == 0) ? wq   : (z == 1) ? wk   : wv;
    const float* __restrict__ bias = (z == 0) ? bq   : (z == 1) ? bk   : bv;

    __shared__ ush Ah[128 * 40];   // pitch 40 shorts = 80B: 2-way alias = free
    __shared__ ush Al[128 * 40];
    __shared__ ush Bh[128 * 40];
    __shared__ ush Bl[128 * 40];

    const int m0 = blockIdx.x * 128;
    const int n0 = blockIdx.y * 128;
    const int t  = threadIdx.x;
    const int wid  = t >> 6;
    const int lane = t & 63;
    const int quad = lane >> 4;
    const int l16  = lane & 15;
    const int wr = (wid >> 1) * 64;
    const int wc = (wid & 1) * 64;

    f32x4 acc[4][4];
    #pragma unroll
    for (int i = 0; i < 4; ++i)
        #pragma unroll
        for (int j = 0; j < 4; ++j) acc[i][j] = (f32x4){0.f, 0.f, 0.f, 0.f};

    for (int k0 = 0; k0 < E_; k0 += 32) {
        __syncthreads();
        #pragma unroll
        for (int i = 0; i < 4; ++i) {
            int idx = t + i * 256;           // 0..1023
            int r = idx >> 3, c4 = idx & 7;  // row, float4-chunk
            float4 a = *(const float4*)&X[(size_t)(m0 + r) * E_ + k0 + c4 * 4];
            float4 w = *(const float4*)&W[(size_t)(n0 + r) * E_ + k0 + c4 * 4];
            unsigned h0, l0, h1, l1;
            cvt_pair(a.x, a.y, h0, l0); cvt_pair(a.z, a.w, h1, l1);
            uint2 vh; vh.x = h0; vh.y = h1;
            uint2 vl; vl.x = l0; vl.y = l1;
            *(uint2*)&Ah[r * 40 + c4 * 4] = vh;
            *(uint2*)&Al[r * 40 + c4 * 4] = vl;
            cvt_pair(w.x, w.y, h0, l0); cvt_pair(w.z, w.w, h1, l1);
            vh.x = h0; vh.y = h1; vl.x = l0; vl.y = l1;
            *(uint2*)&Bh[r * 40 + c4 * 4] = vh;
            *(uint2*)&Bl[r * 40 + c4 * 4] = vl;
        }
        __syncthreads();

        short8 aH[4], aL[4], bH[4], bL[4];
        #pragma unroll
        for (int mi = 0; mi < 4; ++mi) {
            aH[mi] = *(const short8*)&Ah[(wr + mi * 16 + l16) * 40 + quad * 8];
            aL[mi] = *(const short8*)&Al[(wr + mi * 16 + l16) * 40 + quad * 8];
        }
        #pragma unroll
        for (int ni = 0; ni < 4; ++ni) {
            bH[ni] = *(const short8*)&Bh[(wc + ni * 16 + l16) * 40 + quad * 8];
            bL[ni] = *(const short8*)&Bl[(wc + ni * 16 + l16) * 40 + quad * 8];
        }
        #pragma unroll
        for (int mi = 0; mi < 4; ++mi)
            #pragma unroll
            for (int ni = 0; ni < 4; ++ni) {
                acc[mi][ni] = __builtin_amdgcn_mfma_f32_16x16x32_bf16(aH[mi], bL[ni], acc[mi][ni], 0, 0, 0);
                acc[mi][ni] = __builtin_amdgcn_mfma_f32_16x16x32_bf16(aL[mi], bH[ni], acc[mi][ni], 0, 0, 0);
                acc[mi][ni] = __builtin_amdgcn_mfma_f32_16x16x32_bf16(aH[mi], bH[ni], acc[mi][ni], 0, 0, 0);
            }
    }

    // ---- epilogue ----
    const float ln1e4 = 9.210340371976184f;  // ln(10000)
    if (z < 2) {
        ush* __restrict__ Ob = (z == 0) ? Qb : Kb;
        #pragma unroll
        for (int ni = 0; ni < 4; ++ni) {
            const int n = n0 + wc + ni * 16 + l16;
            const int h = n >> 6, d = n & 63;
            const float bw = bias[n];
            const float inv_freq = expf(-((float)(d & 62) / 64.f) * ln1e4);
            const bool even = (d & 1) == 0;
            #pragma unroll
            for (int mi = 0; mi < 4; ++mi) {
                #pragma unroll
                for (int r = 0; r < 4; ++r) {
                    const int m = m0 + wr + mi * 16 + quad * 4 + r;
                    const int bb = m >> 11, s = m & (S_ - 1);
                    float v = acc[mi][ni][r] + bw;
                    float part = __shfl_xor(v, 1);          // pair value (d^1)
                    float sn, cs;
                    sincosf((float)s * inv_freq, &sn, &cs);
                    float rot = even ? (v * cs - part * sn) : (v * cs + part * sn);
                    ush pr = f2b(rot);
                    ush pp = (ush)__shfl_xor((int)pr, 1);   // partner's rotated
                    if (even) {
                        size_t o = (((size_t)bb * H_ + h) * S_ + s) * (size_t)D_ + d;
                        *(unsigned*)&Ob[o] = (unsigned)pr | ((unsigned)pp << 16);
                    }
                }
            }
        }
    } else {
        #pragma unroll
        for (int ni = 0; ni < 4; ++ni) {
            const int n = n0 + wc + ni * 16 + l16;
            const int h = n >> 6, d = n & 63;
            const float bw = bias[n];
            #pragma unroll
            for (int mi = 0; mi < 4; ++mi) {
                const int m = m0 + wr + mi * 16 + quad * 4;  // r=0; r spans 4 consecutive s
                const int bb = m >> 11, sb = m & (S_ - 1);
                ush p0 = f2b(acc[mi][ni][0] + bw);
                ush p1 = f2b(acc[mi][ni][1] + bw);
                ush p2 = f2b(acc[mi][ni][2] + bw);
                ush p3 = f2b(acc[mi][ni][3] + bw);
                size_t o = (((size_t)bb * H_ + h) * D_ + d) * (size_t)S_ + sb;
                uint2 pk; pk.x = (unsigned)p0 | ((unsigned)p1 << 16);
                pk.y = (unsigned)p2 | ((unsigned)p3 << 16);
                *(uint2*)&Vtb[o] = pk;
            }
        }
    }
}

// ---------------------------------------------------------------------------
// Kernel 2: MFMA flash attention (unchanged from round 5 — verified).
// grid (S/64, H, B), block 256 (4 waves, one 16-row Q strip each).
// ---------------------------------------------------------------------------
__global__ __launch_bounds__(256) void attn_kernel(
    const ush* __restrict__ Qb, const ush* __restrict__ Kb, const ush* __restrict__ Vtb,
    const float* __restrict__ pb, const int* __restrict__ mask, const float* __restrict__ coeff,
    float* __restrict__ Att)
{
    __shared__ ush  Ks[64 * 72];
    __shared__ ush  Vt[64 * 72];
    __shared__ ush  Ps[4 * 16 * 72];
    __shared__ float pbk_s[64];
    __shared__ float mb_s[64];

    const int q0 = blockIdx.x * 64;
    const int h  = blockIdx.y;
    const int b  = blockIdx.z;
    const int t  = threadIdx.x;
    const int wid = t >> 6;
    const int lane = t & 63;
    const int quad = lane >> 4;
    const int l16  = lane & 15;

    const int bh = b * H_ + h;
    const float ch = coeff[h];

    const int qrow = q0 + wid * 16 + l16;
    short8 aQ[2];
    #pragma unroll
    for (int ks = 0; ks < 2; ++ks)
        aQ[ks] = *(const short8*)&Qb[((size_t)bh * S_ + qrow) * D_ + quad * 8 + ks * 32];

    float hp[4];
    #pragma unroll
    for (int r = 0; r < 4; ++r)
        hp[r] = ch * pb[b * S_ + q0 + wid * 16 + quad * 4 + r];

    f32x4 O[4];
    #pragma unroll
    for (int g = 0; g < 4; ++g) O[g] = (f32x4){0.f, 0.f, 0.f, 0.f};
    float mrow[4] = {-1e30f, -1e30f, -1e30f, -1e30f};
    float lrow[4] = {0.f, 0.f, 0.f, 0.f};

    for (int kt = 0; kt < S_ / 64; ++kt) {
        const int k0 = kt * 64;
        __syncthreads();
        {
            const uint4* srcK = (const uint4*)(Kb + ((size_t)bh * S_ + k0) * D_);
            #pragma unroll
            for (int it = 0; it < 2; ++it) {
                int idx = t + it * 256;
                int row = idx >> 3, chk = idx & 7;
                *(uint4*)&Ks[row * 72 + chk * 8] = srcK[idx];
                const uint4* srcV = (const uint4*)(Vtb + ((size_t)bh * D_ + row) * S_ + k0);
                *(uint4*)&Vt[row * 72 + chk * 8] = srcV[chk];
            }
        }
        if (t < 64) {
            int gi = b * S_ + k0 + t;
            pbk_s[t] = pb[gi];
            mb_s[t]  = mask[gi] ? 0.f : -1e30f;
        }
        __syncthreads();

        f32x4 Sc[4];
        #pragma unroll
        for (int cg = 0; cg < 4; ++cg) Sc[cg] = (f32x4){0.f, 0.f, 0.f, 0.f};
        #pragma unroll
        for (int ks = 0; ks < 2; ++ks) {
            #pragma unroll
            for (int cg = 0; cg < 4; ++cg) {
                short8 bK = *(const short8*)&Ks[(cg * 16 + l16) * 72 + quad * 8 + ks * 32];
                Sc[cg] = __builtin_amdgcn_mfma_f32_16x16x32_bf16(aQ[ks], bK, Sc[cg], 0, 0, 0);
            }
        }

        float cpb[4], mbv[4];
        #pragma unroll
        for (int cg = 0; cg < 4; ++cg) {
            cpb[cg] = ch * pbk_s[cg * 16 + l16];
            mbv[cg] = mb_s[cg * 16 + l16];
        }
        float mx[4];
        #pragma unroll
        for (int r = 0; r < 4; ++r) mx[r] = -1e30f;
        float sv[4][4];
        #pragma unroll
        for (int cg = 0; cg < 4; ++cg)
            #pragma unroll
            for (int r = 0; r < 4; ++r) {
                float s = Sc[cg][r] * 0.125f + hp[r] - cpb[cg] + mbv[cg];
                sv[cg][r] = s;
                mx[r] = fmaxf(mx[r], s);
            }
        #pragma unroll
        for (int r = 0; r < 4; ++r) {
            mx[r] = fmaxf(mx[r], __shfl_xor(mx[r], 1));
            mx[r] = fmaxf(mx[r], __shfl_xor(mx[r], 2));
            mx[r] = fmaxf(mx[r], __shfl_xor(mx[r], 4));
            mx[r] = fmaxf(mx[r], __shfl_xor(mx[r], 8));
        }
        float alpha[4], psum[4];
        #pragma unroll
        for (int r = 0; r < 4; ++r) {
            float mn = fmaxf(mrow[r], mx[r]);
            alpha[r] = __expf(mrow[r] - mn);
            mrow[r] = mn;
            psum[r] = 0.f;
        }
        #pragma unroll
        for (int cg = 0; cg < 4; ++cg)
            #pragma unroll
            for (int r = 0; r < 4; ++r) {
                float s = sv[cg][r];
                float p = (s > -1e29f) ? __expf(s - mrow[r]) : 0.f;
                sv[cg][r] = p;
                psum[r] += p;
            }
        #pragma unroll
        for (int r = 0; r < 4; ++r) {
            psum[r] += __shfl_xor(psum[r], 1);
            psum[r] += __shfl_xor(psum[r], 2);
            psum[r] += __shfl_xor(psum[r], 4);
            psum[r] += __shfl_xor(psum[r], 8);
            lrow[r] = lrow[r] * alpha[r] + psum[r];
        }

        #pragma unroll
        for (int cg = 0; cg < 4; ++cg)
            #pragma unroll
            for (int r = 0; r < 4; ++r)
                Ps[(wid * 16 + quad * 4 + r) * 72 + cg * 16 + l16] = f2b(sv[cg][r]);
        #pragma unroll
        for (int g = 0; g < 4; ++g)
            #pragma unroll
            for (int r = 0; r < 4; ++r) O[g][r] *= alpha[r];

        #pragma unroll
        for (int ks = 0; ks < 2; ++ks) {
            short8 aP = *(const short8*)&Ps[(wid * 16 + l16) * 72 + quad * 8 + ks * 32];
            #pragma unroll
            for (int g = 0; g < 4; ++g) {
                short8 bV = *(const short8*)&Vt[(g * 16 + l16) * 72 + quad * 8 + ks * 32];
                O[g] = __builtin_amdgcn_mfma_f32_16x16x32_bf16(aP, bV, O[g], 0, 0, 0);
            }
        }
    }

    #pragma unroll
    for (int r = 0; r < 4; ++r) {
        const float rl = 1.f / lrow[r];
        const size_t ob = ((size_t)b * S_ + q0 + wid * 16 + quad * 4 + r) * E_ + h * 64;
        #pragma unroll
        for (int g = 0; g < 4; ++g)
            Att[ob + g * 16 + l16] = O[g][r] * rl;
    }
}

// ---------------------------------------------------------------------------
// Kernel 3: output projection via split-bf16 MFMA. out = Att @ fc_w^T + fc_b.
// Same 128x128 tile structure; fp32 output. grid (M/128, E/128).
// ---------------------------------------------------------------------------
__global__ __launch_bounds__(256) void fc_mfma_kernel(
    const float* __restrict__ Xin, const float* __restrict__ W,
    const float* __restrict__ bias, float* __restrict__ Out)
{
    __shared__ ush Ah[128 * 40];
    __shared__ ush Al[128 * 40];
    __shared__ ush Bh[128 * 40];
    __shared__ ush Bl[128 * 40];

    const int m0 = blockIdx.x * 128;
    const int n0 = blockIdx.y * 128;
    const int t  = threadIdx.x;
    const int wid  = t >> 6;
    const int lane = t & 63;
    const int quad = lane >> 4;
    const int l16  = lane & 15;
    const int wr = (wid >> 1) * 64;
    const int wc = (wid & 1) * 64;

    f32x4 acc[4][4];
    #pragma unroll
    for (int i = 0; i < 4; ++i)
        #pragma unroll
        for (int j = 0; j < 4; ++j) acc[i][j] = (f32x4){0.f, 0.f, 0.f, 0.f};

    for (int k0 = 0; k0 < E_; k0 += 32) {
        __syncthreads();
        #pragma unroll
        for (int i = 0; i < 4; ++i) {
            int idx = t + i * 256;
            int r = idx >> 3, c4 = idx & 7;
            float4 a = *(const float4*)&Xin[(size_t)(m0 + r) * E_ + k0 + c4 * 4];
            float4 w = *(const float4*)&W[(size_t)(n0 + r) * E_ + k0 + c4 * 4];
            unsigned h0, l0, h1, l1;
            cvt_pair(a.x, a.y, h0, l0); cvt_pair(a.z, a.w, h1, l1);
            uint2 vh; vh.x = h0; vh.y = h1;
            uint2 vl; vl.x = l0; vl.y = l1;
            *(uint2*)&Ah[r * 40 + c4 * 4] = vh;
            *(uint2*)&Al[r * 40 + c4 * 4] = vl;
            cvt_pair(w.x, w.y, h0, l0); cvt_pair(w.z, w.w, h1, l1);
            vh.x = h0; vh.y = h1; vl.x = l0; vl.y = l1;
            *(uint2*)&Bh[r * 40 + c4 * 4] = vh;
            *(uint2*)&Bl[r * 40 + c4 * 4] = vl;
        }
        __syncthreads();

        short8 aH[4], aL[4], bH[4], bL[4];
        #pragma unroll
        for (int mi = 0; mi < 4; ++mi) {
            aH[mi] = *(const short8*)&Ah[(wr + mi * 16 + l16) * 40 + quad * 8];
            aL[mi] = *(const short8*)&Al[(wr + mi * 16 + l16) * 40 + quad * 8];
        }
        #pragma unroll
        for (int ni = 0; ni < 4; ++ni) {
            bH[ni] = *(const short8*)&Bh[(wc + ni * 16 + l16) * 40 + quad * 8];
            bL[ni] = *(const short8*)&Bl[(wc + ni * 16 + l16) * 40 + quad * 8];
        }
        #pragma unroll
        for (int mi = 0; mi < 4; ++mi)
            #pragma unroll
            for (int ni = 0; ni < 4; ++ni) {
                acc[mi][ni] = __builtin_amdgcn_mfma_f32_16x16x32_bf16(aH[mi], bL[ni], acc[mi][ni], 0, 0, 0);
                acc[mi][ni] = __builtin_amdgcn_mfma_f32_16x16x32_bf16(aL[mi], bH[ni], acc[mi][ni], 0, 0, 0);
                acc[mi][ni] = __builtin_amdgcn_mfma_f32_16x16x32_bf16(aH[mi], bH[ni], acc[mi][ni], 0, 0, 0);
            }
    }

    #pragma unroll
    for (int ni = 0; ni < 4; ++ni) {
        const int n = n0 + wc + ni * 16 + l16;
        const float bw = bias[n];
        #pragma unroll
        for (int mi = 0; mi < 4; ++mi)
            #pragma unroll
            for (int r = 0; r < 4; ++r) {
                const int m = m0 + wr + mi * 16 + quad * 4 + r;
                Out[(size_t)m * E_ + n] = acc[mi][ni][r] + bw;
            }
    }
}

// ---------------------------------------------------------------------------
extern "C" void kernel_launch(void* const* d_in, const int* in_sizes, int n_in,
                              void* d_out, int out_size, void* d_ws, size_t ws_size,
                              hipStream_t stream)
{
    const float* q_in  = (const float*)d_in[0];
    const float* k_in  = (const float*)d_in[1];
    const float* v_in  = (const float*)d_in[2];
    const float* pb    = (const float*)d_in[3];
    const int*   mask  = (const int*)d_in[4];
    const float* wq    = (const float*)d_in[5];
    const float* bq    = (const float*)d_in[6];
    const float* wk    = (const float*)d_in[7];
    const float* bk    = (const float*)d_in[8];
    const float* wv    = (const float*)d_in[9];
    const float* bv    = (const float*)d_in[10];
    const float* fw    = (const float*)d_in[11];
    const float* fb    = (const float*)d_in[12];
    const float* coeff = (const float*)d_in[13];
    float* out = (float*)d_out;

    const size_t per = (size_t)B_ * H_ * S_ * D_;   // 3,145,728 elements
    float* Att = (float*)d_ws;                       // [B,S,E] fp32
    ush*   Qb  = (ush*)(Att + per);                  // bf16 [B,H,S,D]
    ush*   Kb  = Qb + per;
    ush*   Vtb = Kb + per;                           // bf16 [B,H,D,S]

    qkv_mfma_kernel<<<dim3(M_ / 128, E_ / 128, 3), 256, 0, stream>>>(
        q_in, k_in, v_in, wq, bq, wk, bk, wv, bv, Qb, Kb, Vtb);

    attn_kernel<<<dim3(S_ / 64, H_, B_), 256, 0, stream>>>(
        Qb, Kb, Vtb, pb, mask, coeff, Att);

    fc_mfma_kernel<<<dim3(M_ / 128, E_ / 128), 256, 0, stream>>>(Att, fw, fb, out);
}